// Round 3
// baseline (516.515 us; speedup 1.0000x reference)
//
#include <hip/hip_runtime.h>
#include <stdint.h>
#include <stddef.h>

// ClusterLayer: q = normalize_rows( 1 / (1 + ||z-c||^2) )
// N=200000 rows, D=256, KC=256 clusters. fp32 in/out; cross-term via bf16 MFMA.
// R2: whole B (128KB bf16, fragment-ordered) staged to LDS once per block;
// 1 block/CU, grid-stride tile loop, zero barriers in main loop, linear
// (conflict-free) ds_read_b128. A staged per-tile into 64 VGPRs (16 loads in flight).

#define NT 512
#define D 256
#define KC 256

typedef __attribute__((ext_vector_type(8))) short short8;  // 8 bf16 (4 VGPRs)
typedef __attribute__((ext_vector_type(4))) float f32x4;   // MFMA accumulator

// fp32 -> bf16, round-to-nearest-even (branch-free)
__device__ __forceinline__ short f2bf(float f) {
    uint32_t u = __builtin_bit_cast(uint32_t, f);
    u += 0x7FFFu + ((u >> 16) & 1u);
    return (short)(u >> 16);
}

// csq[k] = ||c_k||^2 ; one wave per cluster row.
__global__ void prep_csq(const float* __restrict__ C, float* __restrict__ csq) {
    const int k = blockIdx.x;
    const int l = threadIdx.x;  // 0..63
    float4 v = *(const float4*)(C + k * D + l * 4);
    float s = v.x * v.x + v.y * v.y + v.z * v.z + v.w * v.w;
#pragma unroll
    for (int off = 32; off > 0; off >>= 1) s += __shfl_down(s, off);
    if (l == 0) csq[k] = s;
}

// Reorder C into MFMA-B fragment order, bf16 (verified in R1):
// Bf[((kk*16 + ct)*64 + lane)*8 + e] = bf16( C[(ct*16 + (lane&15))*D + kk*32 + (lane>>4)*8 + e] )
__global__ void prep_reorder(const float* __restrict__ C, unsigned short* __restrict__ Bf) {
    const int kk = blockIdx.x >> 4;   // 0..7
    const int ct = blockIdx.x & 15;   // 0..15
    const int lane = threadIdx.x;     // 0..63
    const int l15 = lane & 15;
    const int lg = lane >> 4;
    const float* src = C + (size_t)(ct * 16 + l15) * D + kk * 32 + lg * 8;
    float4 a0 = *(const float4*)(src);
    float4 a1 = *(const float4*)(src + 4);
    ushort4 p0, p1;
    p0.x = (unsigned short)f2bf(a0.x); p0.y = (unsigned short)f2bf(a0.y);
    p0.z = (unsigned short)f2bf(a0.z); p0.w = (unsigned short)f2bf(a0.w);
    p1.x = (unsigned short)f2bf(a1.x); p1.y = (unsigned short)f2bf(a1.y);
    p1.z = (unsigned short)f2bf(a1.z); p1.w = (unsigned short)f2bf(a1.w);
    unsigned short* dst = Bf + ((size_t)(kk * 16 + ct) * 64 + lane) * 8;
    *(ushort4*)(dst) = p0;
    *(ushort4*)(dst + 4) = p1;
}

// 8 waves/block, 1 block/CU (128KB LDS). Stage B to LDS once, then grid-stride
// over 16-row tiles with no barriers. Each wave owns full rows -> intra-wave
// row normalization (verified epilogue from R1).
__global__ void __launch_bounds__(NT, 2)
main_kernel(const float* __restrict__ z,
            const uint4* __restrict__ Bf,
            const float* __restrict__ csq,
            float* __restrict__ out, int ntiles) {
    __shared__ uint4 ldsB[8192];  // 128KB: fragment-ordered bf16 B

    const int tid  = threadIdx.x;
    const int lane = tid & 63;
    const int wave = tid >> 6;
    const int l15  = lane & 15;
    const int lg   = lane >> 4;          // 0..3

    // stage whole B once (16 x dwordx4 per thread), linear -> conflict-free
#pragma unroll
    for (int i = 0; i < 16; ++i) ldsB[tid + i * NT] = Bf[tid + i * NT];
    __syncthreads();

    // c_sq for this lane's 16 columns (col = ct*16 + l15), kept in regs
    float csqr[16];
#pragma unroll
    for (int ct = 0; ct < 16; ++ct) csqr[ct] = csq[ct * 16 + l15];

    const char* ldsb = (const char*)ldsB;
    const int totalWaves = gridDim.x * (NT / 64);
    const int gwid = blockIdx.x * (NT / 64) + wave;

    for (int t = gwid; t < ntiles; t += totalWaves) {
        const int row0 = t * 16;
        const float* zrow = z + (size_t)(row0 + l15) * D + lg * 8;

        // stage the wave's whole A tile: 16 loads in flight, one HBM latency/tile
        float4 A0[8], A1[8];
#pragma unroll
        for (int kk = 0; kk < 8; ++kk) {
            A0[kk] = *(const float4*)(zrow + kk * 32);
            A1[kk] = *(const float4*)(zrow + kk * 32 + 4);
        }

        f32x4 acc[16];
        const f32x4 zero4 = {0.f, 0.f, 0.f, 0.f};
#pragma unroll
        for (int ct = 0; ct < 16; ++ct) acc[ct] = zero4;
        float zsq_part = 0.f;

#pragma unroll
        for (int kk = 0; kk < 8; ++kk) {
            float4 a0 = A0[kk], a1 = A1[kk];
            zsq_part += a0.x * a0.x + a0.y * a0.y + a0.z * a0.z + a0.w * a0.w +
                        a1.x * a1.x + a1.y * a1.y + a1.z * a1.z + a1.w * a1.w;
            short8 af;
            af[0] = f2bf(a0.x); af[1] = f2bf(a0.y); af[2] = f2bf(a0.z); af[3] = f2bf(a0.w);
            af[4] = f2bf(a1.x); af[5] = f2bf(a1.y); af[6] = f2bf(a1.z); af[7] = f2bf(a1.w);
#pragma unroll
            for (int ct = 0; ct < 16; ++ct) {
                // linear per-lane address: base + lane*16 -> zero bank conflicts
                short8 bf = *(const short8*)(ldsb + (((kk * 16 + ct) << 10) + (lane << 4)));
                acc[ct] = __builtin_amdgcn_mfma_f32_16x16x32_bf16(af, bf, acc[ct], 0, 0, 0);
            }
        }

        // ||z_row||^2: lane holds partial for row l15; sum over the 4 lane-groups
        float zsq = zsq_part;
        zsq += __shfl_xor(zsq, 16);
        zsq += __shfl_xor(zsq, 32);
        float zsqj[4];
#pragma unroll
        for (int j = 0; j < 4; ++j) zsqj[j] = __shfl(zsq, lg * 4 + j);

        // q = 1/(1+dist); accumulate per-lane partial row sums
        float rs[4] = {0.f, 0.f, 0.f, 0.f};
#pragma unroll
        for (int ct = 0; ct < 16; ++ct) {
#pragma unroll
            for (int j = 0; j < 4; ++j) {
                float dist = zsqj[j] + csqr[ct] - 2.0f * acc[ct][j];
                dist = fmaxf(dist, 0.f);
                float qv = 1.0f / (1.0f + dist);
                acc[ct][j] = qv;
                rs[j] += qv;
            }
        }
        // reduce row sums across the 16-lane column group
#pragma unroll
        for (int j = 0; j < 4; ++j) {
            float s = rs[j];
            s += __shfl_xor(s, 1);
            s += __shfl_xor(s, 2);
            s += __shfl_xor(s, 4);
            s += __shfl_xor(s, 8);
            rs[j] = 1.0f / s;
        }
        // store: lane writes col ct*16+l15 of rows row0 + lg*4 + j
#pragma unroll
        for (int j = 0; j < 4; ++j) {
            float* orow = out + (size_t)(row0 + lg * 4 + j) * KC + l15;
#pragma unroll
            for (int ct = 0; ct < 16; ++ct) orow[ct * 16] = acc[ct][j] * rs[j];
        }
    }
}

extern "C" void kernel_launch(void* const* d_in, const int* in_sizes, int n_in,
                              void* d_out, int out_size, void* d_ws, size_t ws_size,
                              hipStream_t stream) {
    const float* zp = (const float*)d_in[0];
    const float* Cp = (const float*)d_in[1];
    const int N = in_sizes[0] / D;  // 200000
    unsigned short* Bf = (unsigned short*)d_ws;                          // 128KB bf16 frag-ordered
    float* csq = (float*)((char*)d_ws + (size_t)KC * D * sizeof(unsigned short));  // 1KB

    prep_csq<<<KC, 64, 0, stream>>>(Cp, csq);
    prep_reorder<<<128, 64, 0, stream>>>(Cp, Bf);

    const int ntiles = (N + 15) / 16;          // 12500
    main_kernel<<<256, NT, 0, stream>>>(zp, (const uint4*)Bf, csq, (float*)d_out, ntiles);
}

// Round 4
// 494.476 us; speedup vs baseline: 1.0446x; 1.0446x over previous
//
#include <hip/hip_runtime.h>
#include <stdint.h>
#include <stddef.h>

// ClusterLayer: q = normalize_rows( 1 / (1 + ||z-c||^2) )
// N=200000 rows, D=256, KC=256 clusters. fp32 in/out; cross-term via bf16 MFMA.
// R3: whole B (128KB bf16, fragment-ordered) staged to LDS once per block;
// 1 block/CU, grid-stride tile loop, zero barriers in main loop, linear
// conflict-free ds_read_b128. A loads: 6xfloat4 rolling pipeline (2 k-steps
// lookahead, pipelined ACROSS tiles) -> no register spill (R2's failure mode).

#define NT 512
#define D 256
#define KC 256

typedef __attribute__((ext_vector_type(8))) short short8;  // 8 bf16 (4 VGPRs)
typedef __attribute__((ext_vector_type(4))) float f32x4;   // MFMA accumulator

// fp32 -> bf16, round-to-nearest-even (branch-free)
__device__ __forceinline__ short f2bf(float f) {
    uint32_t u = __builtin_bit_cast(uint32_t, f);
    u += 0x7FFFu + ((u >> 16) & 1u);
    return (short)(u >> 16);
}

// csq[k] = ||c_k||^2 ; one wave per cluster row.
__global__ void prep_csq(const float* __restrict__ C, float* __restrict__ csq) {
    const int k = blockIdx.x;
    const int l = threadIdx.x;  // 0..63
    float4 v = *(const float4*)(C + k * D + l * 4);
    float s = v.x * v.x + v.y * v.y + v.z * v.z + v.w * v.w;
#pragma unroll
    for (int off = 32; off > 0; off >>= 1) s += __shfl_down(s, off);
    if (l == 0) csq[k] = s;
}

// Reorder C into MFMA-B fragment order, bf16 (verified R1/R2):
// Bf[((kk*16 + ct)*64 + lane)*8 + e] = bf16( C[(ct*16 + (lane&15))*D + kk*32 + (lane>>4)*8 + e] )
__global__ void prep_reorder(const float* __restrict__ C, unsigned short* __restrict__ Bf) {
    const int kk = blockIdx.x >> 4;   // 0..7
    const int ct = blockIdx.x & 15;   // 0..15
    const int lane = threadIdx.x;     // 0..63
    const int l15 = lane & 15;
    const int lg = lane >> 4;
    const float* src = C + (size_t)(ct * 16 + l15) * D + kk * 32 + lg * 8;
    float4 a0 = *(const float4*)(src);
    float4 a1 = *(const float4*)(src + 4);
    ushort4 p0, p1;
    p0.x = (unsigned short)f2bf(a0.x); p0.y = (unsigned short)f2bf(a0.y);
    p0.z = (unsigned short)f2bf(a0.z); p0.w = (unsigned short)f2bf(a0.w);
    p1.x = (unsigned short)f2bf(a1.x); p1.y = (unsigned short)f2bf(a1.y);
    p1.z = (unsigned short)f2bf(a1.z); p1.w = (unsigned short)f2bf(a1.w);
    unsigned short* dst = Bf + ((size_t)(kk * 16 + ct) * 64 + lane) * 8;
    *(ushort4*)(dst) = p0;
    *(ushort4*)(dst + 4) = p1;
}

__global__ void __launch_bounds__(NT, 2)
main_kernel(const float* __restrict__ z,
            const uint4* __restrict__ Bf,
            const float* __restrict__ csq,
            float* __restrict__ out, int ntiles) {
    __shared__ uint4 ldsB[8192];  // 128KB: fragment-ordered bf16 B

    const int tid  = threadIdx.x;
    const int lane = tid & 63;
    const int wave = tid >> 6;
    const int l15  = lane & 15;
    const int lg   = lane >> 4;          // 0..3

    // stage whole B once (16 x dwordx4 per thread), linear -> conflict-free
#pragma unroll
    for (int i = 0; i < 16; ++i) ldsB[tid + i * NT] = Bf[tid + i * NT];
    __syncthreads();

    // c_sq for this lane's 16 columns (col = ct*16 + l15), kept in regs
    float csqr[16];
#pragma unroll
    for (int ct = 0; ct < 16; ++ct) csqr[ct] = csq[ct * 16 + l15];

    const char* ldsb = (const char*)ldsB;
    const int stride = gridDim.x * (NT / 64);
    int t = blockIdx.x * (NT / 64) + wave;   // grid (2048 waves) <= ntiles: always valid

    const float* zrow = z + (size_t)(t * 16 + l15) * D + lg * 8;
    // rolling A pipeline: c = current k-step, d = next, e = loading (2 ahead)
    float4 c0 = *(const float4*)(zrow),      c1 = *(const float4*)(zrow + 4);
    float4 d0 = *(const float4*)(zrow + 32), d1 = *(const float4*)(zrow + 36);

    while (true) {
        const int tn = t + stride;
        const bool more = tn < ntiles;
        const float* zrow_n = more ? z + (size_t)(tn * 16 + l15) * D + lg * 8 : zrow;

        f32x4 acc[16];
        const f32x4 zero4 = {0.f, 0.f, 0.f, 0.f};
#pragma unroll
        for (int ct = 0; ct < 16; ++ct) acc[ct] = zero4;
        float zsq_part = 0.f;

#pragma unroll
        for (int kk = 0; kk < 8; ++kk) {
            // prefetch 2 k-steps ahead; kk=6,7 fetch NEXT tile's k-steps 0,1
            const float* pf = (kk < 6) ? (zrow + (kk + 2) * 32) : (zrow_n + (kk - 6) * 32);
            float4 e0 = *(const float4*)(pf);
            float4 e1 = *(const float4*)(pf + 4);

            zsq_part += c0.x * c0.x + c0.y * c0.y + c0.z * c0.z + c0.w * c0.w +
                        c1.x * c1.x + c1.y * c1.y + c1.z * c1.z + c1.w * c1.w;
            short8 af;
            af[0] = f2bf(c0.x); af[1] = f2bf(c0.y); af[2] = f2bf(c0.z); af[3] = f2bf(c0.w);
            af[4] = f2bf(c1.x); af[5] = f2bf(c1.y); af[6] = f2bf(c1.z); af[7] = f2bf(c1.w);
#pragma unroll
            for (int ct = 0; ct < 16; ++ct) {
                // linear per-lane address: base + lane*16 -> zero bank conflicts
                short8 bf = *(const short8*)(ldsb + (((kk * 16 + ct) << 10) + (lane << 4)));
                acc[ct] = __builtin_amdgcn_mfma_f32_16x16x32_bf16(af, bf, acc[ct], 0, 0, 0);
            }
            c0 = d0; c1 = d1; d0 = e0; d1 = e1;
        }
        // c/d now hold next tile's k-steps 0,1

        // ||z_row||^2: lane holds partial for row l15; sum over the 4 lane-groups
        float zsq = zsq_part;
        zsq += __shfl_xor(zsq, 16);
        zsq += __shfl_xor(zsq, 32);
        float zsqj[4];
#pragma unroll
        for (int j = 0; j < 4; ++j) zsqj[j] = __shfl(zsq, lg * 4 + j);

        // q = 1/(1+dist); accumulate per-lane partial row sums
        float rs[4] = {0.f, 0.f, 0.f, 0.f};
#pragma unroll
        for (int ct = 0; ct < 16; ++ct) {
#pragma unroll
            for (int j = 0; j < 4; ++j) {
                float dist = zsqj[j] + csqr[ct] - 2.0f * acc[ct][j];
                dist = fmaxf(dist, 0.f);
                float qv = 1.0f / (1.0f + dist);
                acc[ct][j] = qv;
                rs[j] += qv;
            }
        }
        // reduce row sums across the 16-lane column group
#pragma unroll
        for (int j = 0; j < 4; ++j) {
            float s = rs[j];
            s += __shfl_xor(s, 1);
            s += __shfl_xor(s, 2);
            s += __shfl_xor(s, 4);
            s += __shfl_xor(s, 8);
            rs[j] = 1.0f / s;
        }
        // store: lane writes col ct*16+l15 of rows t*16 + lg*4 + j
#pragma unroll
        for (int j = 0; j < 4; ++j) {
            float* orow = out + (size_t)(t * 16 + lg * 4 + j) * KC + l15;
#pragma unroll
            for (int ct = 0; ct < 16; ++ct) orow[ct * 16] = acc[ct][j] * rs[j];
        }

        if (!more) break;
        t = tn;
        zrow = zrow_n;
    }
}

extern "C" void kernel_launch(void* const* d_in, const int* in_sizes, int n_in,
                              void* d_out, int out_size, void* d_ws, size_t ws_size,
                              hipStream_t stream) {
    const float* zp = (const float*)d_in[0];
    const float* Cp = (const float*)d_in[1];
    const int N = in_sizes[0] / D;  // 200000
    unsigned short* Bf = (unsigned short*)d_ws;                          // 128KB bf16 frag-ordered
    float* csq = (float*)((char*)d_ws + (size_t)KC * D * sizeof(unsigned short));  // 1KB

    prep_csq<<<KC, 64, 0, stream>>>(Cp, csq);
    prep_reorder<<<128, 64, 0, stream>>>(Cp, Bf);

    const int ntiles = (N + 15) / 16;          // 12500
    main_kernel<<<256, NT, 0, stream>>>(zp, (const uint4*)Bf, csq, (float*)d_out, ntiles);
}

// Round 5
// 115.895 us; speedup vs baseline: 4.4568x; 4.2666x over previous
//
#include <hip/hip_runtime.h>
#include <stdint.h>
#include <stddef.h>

// ClusterLayer: q = normalize_rows( 1 / (1 + ||z-c||^2) )
// N=200000 rows, D=256, KC=256 clusters. fp32 in/out; cross-term via bf16 MFMA.
// R4: whole B (128KB bf16, fragment-ordered) LDS-resident per block. Each
// 16-row tile co-owned by a PAIR of waves (128 cols each) -> acc[8] = 32 regs,
// ~100 VGPR total: kills R2/R3's accumulator scratch-spill (their 740MB fetch /
// 408MB write signature). Row-sum exchange: 16 floats via LDS + raw s_barrier
// with lgkmcnt-only wait (vmcnt NOT drained -> next-tile A prefetch survives).

#define NT 512
#define GRID 256
#define D 256
#define KC 256

typedef __attribute__((ext_vector_type(8))) short short8;  // 8 bf16 (4 VGPRs)
typedef __attribute__((ext_vector_type(4))) float f32x4;   // MFMA accumulator

// fp32 -> bf16, round-to-nearest-even (branch-free)
__device__ __forceinline__ short f2bf(float f) {
    uint32_t u = __builtin_bit_cast(uint32_t, f);
    u += 0x7FFFu + ((u >> 16) & 1u);
    return (short)(u >> 16);
}

// csq[k] = ||c_k||^2 ; one wave per cluster row.
__global__ void prep_csq(const float* __restrict__ C, float* __restrict__ csq) {
    const int k = blockIdx.x;
    const int l = threadIdx.x;  // 0..63
    float4 v = *(const float4*)(C + k * D + l * 4);
    float s = v.x * v.x + v.y * v.y + v.z * v.z + v.w * v.w;
#pragma unroll
    for (int off = 32; off > 0; off >>= 1) s += __shfl_down(s, off);
    if (l == 0) csq[k] = s;
}

// Reorder C into MFMA-B fragment order, bf16 (verified R1-R3):
// Bf[((kk*16 + ct)*64 + lane)*8 + e] = bf16( C[(ct*16 + (lane&15))*D + kk*32 + (lane>>4)*8 + e] )
__global__ void prep_reorder(const float* __restrict__ C, unsigned short* __restrict__ Bf) {
    const int kk = blockIdx.x >> 4;   // 0..7
    const int ct = blockIdx.x & 15;   // 0..15
    const int lane = threadIdx.x;     // 0..63
    const int l15 = lane & 15;
    const int lg = lane >> 4;
    const float* src = C + (size_t)(ct * 16 + l15) * D + kk * 32 + lg * 8;
    float4 a0 = *(const float4*)(src);
    float4 a1 = *(const float4*)(src + 4);
    ushort4 p0, p1;
    p0.x = (unsigned short)f2bf(a0.x); p0.y = (unsigned short)f2bf(a0.y);
    p0.z = (unsigned short)f2bf(a0.z); p0.w = (unsigned short)f2bf(a0.w);
    p1.x = (unsigned short)f2bf(a1.x); p1.y = (unsigned short)f2bf(a1.y);
    p1.z = (unsigned short)f2bf(a1.z); p1.w = (unsigned short)f2bf(a1.w);
    unsigned short* dst = Bf + ((size_t)(kk * 16 + ct) * 64 + lane) * 8;
    *(ushort4*)(dst) = p0;
    *(ushort4*)(dst + 4) = p1;
}

__global__ void __launch_bounds__(NT)
main_kernel(const float* __restrict__ z,
            const uint4* __restrict__ Bf,
            const float* __restrict__ csq,
            float* __restrict__ out, int ntiles, int niter) {
    __shared__ uint4 ldsB[8192];                       // 128KB fragment-ordered bf16 B
    __shared__ __align__(16) float ldsRS[2][8][16];    // [parity][wave][row] row-sum exchange

    const int tid  = threadIdx.x;
    const int lane = tid & 63;
    const int wave = tid >> 6;
    const int l15  = lane & 15;
    const int lg   = lane >> 4;          // 0..3
    const int half = wave & 1;           // which 128-col half of the tile
    const int pair = wave >> 1;          // tile-pair index within block (0..3)

    // stage whole B once (16 x dwordx4 per thread), linear -> conflict-free
#pragma unroll
    for (int i = 0; i < 16; ++i) ldsB[tid + i * NT] = Bf[tid + i * NT];
    __syncthreads();

    // c_sq for this lane's 8 columns (col = half*128 + ct*16 + l15)
    float csqr[8];
#pragma unroll
    for (int ct = 0; ct < 8; ++ct) csqr[ct] = csq[half * 128 + ct * 16 + l15];

    const char* ldsb = (const char*)ldsB;
    const int laneoff = (lane << 4) + (half << 13);  // lane*16 + half*8 frag-blocks

    const int tstride = GRID * 4;                    // 1024 tile-pairs per sweep
    int t = blockIdx.x * 4 + pair;                   // < 1024 <= ntiles: initially valid

    const float* zrow = z + (size_t)(t * 16 + l15) * D + lg * 8;
    // rolling A pipeline: c = current k-step, d = next (2-step lookahead)
    float4 c0 = *(const float4*)(zrow),      c1 = *(const float4*)(zrow + 4);
    float4 d0 = *(const float4*)(zrow + 32), d1 = *(const float4*)(zrow + 36);

    for (int i = 0; i < niter; ++i) {
        const bool active = t < ntiles;
        const int tn = t + tstride;
        const int tnc = (tn < ntiles) ? tn : (ntiles - 1);
        const float* zrow_n = z + (size_t)(tnc * 16 + l15) * D + lg * 8;

        f32x4 acc[8];
        const f32x4 zero4 = {0.f, 0.f, 0.f, 0.f};
#pragma unroll
        for (int ct = 0; ct < 8; ++ct) acc[ct] = zero4;
        float zsq_part = 0.f;

#pragma unroll
        for (int kk = 0; kk < 8; ++kk) {
            // prefetch 2 k-steps ahead; kk=6,7 fetch NEXT tile's k-steps 0,1
            const float* pf = (kk < 6) ? (zrow + (kk + 2) * 32) : (zrow_n + (kk - 6) * 32);
            float4 e0 = *(const float4*)(pf);
            float4 e1 = *(const float4*)(pf + 4);

            zsq_part += c0.x * c0.x + c0.y * c0.y + c0.z * c0.z + c0.w * c0.w +
                        c1.x * c1.x + c1.y * c1.y + c1.z * c1.z + c1.w * c1.w;
            short8 af;
            af[0] = f2bf(c0.x); af[1] = f2bf(c0.y); af[2] = f2bf(c0.z); af[3] = f2bf(c0.w);
            af[4] = f2bf(c1.x); af[5] = f2bf(c1.y); af[6] = f2bf(c1.z); af[7] = f2bf(c1.w);
#pragma unroll
            for (int ct = 0; ct < 8; ++ct) {
                // linear per-lane address -> zero bank conflicts
                short8 bf = *(const short8*)(ldsb + laneoff + ((kk * 16 + ct) << 10));
                acc[ct] = __builtin_amdgcn_mfma_f32_16x16x32_bf16(af, bf, acc[ct], 0, 0, 0);
            }
            c0 = d0; c1 = d1; d0 = e0; d1 = e1;
        }
        // c/d now hold next tile's k-steps 0,1 (loads still in flight past barrier)

        // ||z_row||^2: lane holds partial for row l15; sum over the 4 lane-groups
        float zsq = zsq_part;
        zsq += __shfl_xor(zsq, 16);
        zsq += __shfl_xor(zsq, 32);
        float zsqj[4];
#pragma unroll
        for (int j = 0; j < 4; ++j) zsqj[j] = __shfl(zsq, lg * 4 + j);

        // q = 1/(1+dist); per-lane partial row sums over this wave's 8 col-frags
        float rs[4] = {0.f, 0.f, 0.f, 0.f};
#pragma unroll
        for (int ct = 0; ct < 8; ++ct) {
#pragma unroll
            for (int j = 0; j < 4; ++j) {
                float dist = zsqj[j] + csqr[ct] - 2.0f * acc[ct][j];
                dist = fmaxf(dist, 0.f);
                float qv = 1.0f / (1.0f + dist);
                acc[ct][j] = qv;
                rs[j] += qv;
            }
        }
        // reduce over the 16-lane column group -> this wave's 128-col row sums
#pragma unroll
        for (int j = 0; j < 4; ++j) {
            float s = rs[j];
            s += __shfl_xor(s, 1);
            s += __shfl_xor(s, 2);
            s += __shfl_xor(s, 4);
            s += __shfl_xor(s, 8);
            rs[j] = s;
        }
        // exchange with partner wave (other 128 cols), parity double-buffered
        if (l15 == 0) {
            float4 w = {rs[0], rs[1], rs[2], rs[3]};
            *(float4*)&ldsRS[i & 1][wave][lg * 4] = w;
        }
        asm volatile("s_waitcnt lgkmcnt(0)" ::: "memory");
        __builtin_amdgcn_s_barrier();          // raw: vmcnt NOT drained
        __builtin_amdgcn_sched_barrier(0);
        float4 prs = *(const float4*)&ldsRS[i & 1][wave ^ 1][lg * 4];
        float inv[4];
        inv[0] = 1.0f / (rs[0] + prs.x);
        inv[1] = 1.0f / (rs[1] + prs.y);
        inv[2] = 1.0f / (rs[2] + prs.z);
        inv[3] = 1.0f / (rs[3] + prs.w);

        if (active) {
#pragma unroll
            for (int j = 0; j < 4; ++j) {
                float* orow = out + (size_t)(t * 16 + lg * 4 + j) * KC + half * 128 + l15;
#pragma unroll
                for (int ct = 0; ct < 8; ++ct) orow[ct * 16] = acc[ct][j] * inv[j];
            }
        }
        t = tn;
        zrow = zrow_n;
    }
}

extern "C" void kernel_launch(void* const* d_in, const int* in_sizes, int n_in,
                              void* d_out, int out_size, void* d_ws, size_t ws_size,
                              hipStream_t stream) {
    const float* zp = (const float*)d_in[0];
    const float* Cp = (const float*)d_in[1];
    const int N = in_sizes[0] / D;  // 200000
    unsigned short* Bf = (unsigned short*)d_ws;                          // 128KB bf16 frag-ordered
    float* csq = (float*)((char*)d_ws + (size_t)KC * D * sizeof(unsigned short));  // 1KB

    prep_csq<<<KC, 64, 0, stream>>>(Cp, csq);
    prep_reorder<<<128, 64, 0, stream>>>(Cp, Bf);

    const int ntiles = (N + 15) / 16;                        // 12500
    const int niter = (ntiles + GRID * 4 - 1) / (GRID * 4);  // 13
    main_kernel<<<GRID, NT, 0, stream>>>(zp, (const uint4*)Bf, csq, (float*)d_out, ntiles, niter);
}